// Round 8
// baseline (421.388 us; speedup 1.0000x reference)
//
#include <hip/hip_runtime.h>
#include <hip/hip_bf16.h>
#include <math.h>

typedef short bf16x8 __attribute__((ext_vector_type(8)));
typedef float f32x4 __attribute__((ext_vector_type(4)));
typedef __hip_bfloat16 bf16;
typedef unsigned long long ull;

#define NW 8    // row windows (= XCDs; window w runs on xcd w via bid&7)
#define BSL 32  // edge slices per window (= CUs per XCD)

static __device__ __forceinline__ float bf2f(ushort u) {
    unsigned int x = ((unsigned int)u) << 16;
    return __builtin_bit_cast(float, x);
}
static __device__ __forceinline__ ushort f2bf(float f) {
    bf16 h = __float2bfloat16(f);
    return __builtin_bit_cast(ushort, h);
}

// ---------------- CSR build: windowed counting sort, no global atomics ----------------

// per-(window,slice) LDS histogram; 2 rows packed per uint (ushort counts)
__global__ __launch_bounds__(1024) void k_hist(const int* __restrict__ row,
                                               uint* __restrict__ histU,
                                               int E, int N, int W) {
    __shared__ uint h[6400];
    int bid = blockIdx.x, w = bid & 7, b = bid >> 3;
    int w0 = w * W, WH = W >> 1;
    int wlen = min(W, N - w0);
    for (int t = threadIdx.x; t < WH; t += 1024) h[t] = 0;
    __syncthreads();
    int e0 = (int)((long long)E * b / BSL);
    int e1 = (int)((long long)E * (b + 1) / BSL);
    for (int i = e0 + threadIdx.x; i < e1; i += 1024) {
        int r = __builtin_nontemporal_load(&row[i]) - w0;
        if ((unsigned)r < (unsigned)wlen)
            atomicAdd(&h[r >> 1], 1u << ((r & 1) << 4));
    }
    __syncthreads();
    uint* dst = histU + (size_t)(w * BSL + b) * WH;
    for (int t = threadIdx.x; t < WH; t += 1024) dst[t] = h[t];
}

// per row-pair: per-slice counts -> per-slice exclusive offsets (in place); deg+dinv
__global__ __launch_bounds__(256) void k_rowsum(uint* __restrict__ histU,
                                                int* __restrict__ deg,
                                                float* __restrict__ dinv,
                                                int N, int W) {
    int q = blockIdx.x * 256 + threadIdx.x;
    int NH = (N + 1) >> 1;
    if (q >= NH) return;
    int r0 = 2 * q;
    int w = r0 / W, WH = W >> 1;
    int qw = (r0 - w * W) >> 1;
    uint run0 = 0, run1 = 0;
    uint* p = histU + (size_t)(w * BSL) * WH + qw;
#pragma unroll 8
    for (int b = 0; b < BSL; ++b) {
        uint v = p[(size_t)b * WH];
        p[(size_t)b * WH] = run0 | (run1 << 16);
        run0 += v & 0xffffu;
        run1 += v >> 16;
    }
    int d0 = (int)run0, d1 = (int)run1;
    deg[r0] = d0;
    dinv[r0] = d0 > 0 ? 1.0f / sqrtf((float)d0) : 0.0f;
    if (r0 + 1 < N) {
        deg[r0 + 1] = d1;
        dinv[r0 + 1] = d1 > 0 ? 1.0f / sqrtf((float)d1) : 0.0f;
    }
}

// start = exclusive prefix of deg (wave-aggregated atomic alloc)
__global__ __launch_bounds__(256) void k_alloc(const int* __restrict__ deg,
                                               int* __restrict__ start,
                                               int* counter, int N) {
    int i = blockIdx.x * 256 + threadIdx.x;
    int lane = threadIdx.x & 63;
    int d = (i < N) ? deg[i] : 0;
    int v = d;
#pragma unroll
    for (int off = 1; off < 64; off <<= 1) {
        int t = __shfl_up(v, off);
        if (lane >= off) v += t;
    }
    int total = __shfl(v, 63);
    int base = 0;
    if (lane == 63) base = atomicAdd(counter, total);
    base = __shfl(base, 63);
    if (i < N) start[i] = base + v - d;
}

// deterministic fill: slot = start[r] + slice-offset + LDS cursor
__global__ __launch_bounds__(1024) void k_fill2(const int* __restrict__ row,
                                                const int* __restrict__ col,
                                                const int* __restrict__ start,
                                                const uint* __restrict__ histU,
                                                const float* __restrict__ dinv,
                                                int2* __restrict__ ecc,
                                                int E, int N, int W) {
    __shared__ int cur[12800];
    int bid = blockIdx.x, w = bid & 7, b = bid >> 3;
    int w0 = w * W, WH = W >> 1;
    int wlen = min(W, N - w0);
    const uint* hb = histU + (size_t)(w * BSL + b) * WH;
    for (int j = threadIdx.x; 2 * j < wlen; j += 1024) {
        uint off = __builtin_nontemporal_load(&hb[j]);
        int r0 = w0 + 2 * j;
        cur[2 * j] = start[r0] + (int)(off & 0xffffu);
        if (2 * j + 1 < wlen) cur[2 * j + 1] = start[r0 + 1] + (int)(off >> 16);
    }
    __syncthreads();
    int e0 = (int)((long long)E * b / BSL);
    int e1 = (int)((long long)E * (b + 1) / BSL);
    for (int i = e0 + threadIdx.x; i < e1; i += 1024) {
        int r = __builtin_nontemporal_load(&row[i]) - w0;
        if ((unsigned)r < (unsigned)wlen) {
            int c = __builtin_nontemporal_load(&col[i]);
            int p = atomicAdd(&cur[r], 1);
            int2 pk;
            pk.x = c;
            pk.y = __float_as_int(dinv[c]);
            ecc[p] = pk;
        }
    }
}

// ---------------- layout prep ----------------
__global__ __launch_bounds__(256) void k_pad_x(const float* __restrict__ x,
                                               ushort* __restrict__ xb, int N) {
    int t = blockIdx.x * 256 + threadIdx.x;
    if (t >= N * 64) return;
    int i = t >> 6, c = t & 63;
    float v = (c < 50) ? x[(size_t)i * 50 + c] : 0.f;
    xb[t] = f2bf(v);
}

__global__ __launch_bounds__(256) void k_wt(const float* __restrict__ W1,
                                            const float* __restrict__ W2,
                                            ushort* __restrict__ Wt1,
                                            ushort* __restrict__ Wt2) {
    int t = blockIdx.x * 256 + threadIdx.x;
    if (t >= 2 * 64 * 192) return;
    int half = t / (64 * 192), u = t % (64 * 192);
    int cout = u / 192, k = u % 192;
    int arr = k >> 6, c = k & 63;
    if (half == 0) {
        float v = (c < 50) ? W1[(size_t)(arr * 50 + c) * 50 + cout] : 0.f;
        Wt1[u] = f2bf(v);
    } else {
        float v = (c < 50 && cout < 40) ? W2[(size_t)(arr * 50 + c) * 40 + cout] : 0.f;
        Wt2[u] = f2bf(v);
    }
}

// ---------------- L_hat multiply: one ROW per HALF-WAVE ----------------
// Half-wave h (32 lanes) owns row i = blk*8 + wid*2 + h entirely: lane c holds
// channels 2c,2c+1 (uint). One gather instr = 1 line per half-wave. The 8-deep
// pipelined path engages at d>=8 (vs d>=32 before), so ~16 lines stay in
// flight per wave for nearly all rows. Headers via nontemporal 8B loads.
__global__ __launch_bounds__(256) void k_lmul(const int* __restrict__ start,
                                              const int* __restrict__ deg,
                                              const int2* __restrict__ ecc,
                                              const float* __restrict__ dinv,
                                              const ushort* __restrict__ v,
                                              const ushort* __restrict__ other,
                                              ushort* __restrict__ out, int N,
                                              float a, float bc) {
    int wid = threadIdx.x >> 6, lane = threadIdx.x & 63;
    int h = lane >> 5, c = lane & 31;
    int i = blockIdx.x * 8 + wid * 2 + h;
    if (i >= N) return;
    int s = start[i];
    int d = deg[i];
    const char* vB = (const char*)v;
    const ull* eccq = (const ull*)ecc;
    float acc0 = 0.f, acc1 = 0.f;
    int k = 0;

    if (d >= 8) {
        ull e[8];
#pragma unroll
        for (int j = 0; j < 8; ++j) e[j] = __builtin_nontemporal_load(&eccq[s + j]);
        for (; k + 16 <= d; k += 8) {
            ull n[8];
#pragma unroll
            for (int j = 0; j < 8; ++j) n[j] = __builtin_nontemporal_load(&eccq[s + k + 8 + j]);
            uint g[8];
#pragma unroll
            for (int j = 0; j < 8; ++j)
                g[j] = *(const uint*)(vB + ((size_t)(uint)e[j] << 7) + (c << 2));
#pragma unroll
            for (int j = 0; j < 8; ++j) {
                float w = __int_as_float((int)(e[j] >> 32));
                acc0 += w * bf2f((ushort)g[j]);
                acc1 += w * bf2f((ushort)(g[j] >> 16));
            }
#pragma unroll
            for (int j = 0; j < 8; ++j) e[j] = n[j];
        }
        {   // drain preloaded block [k, k+8)
            uint g[8];
#pragma unroll
            for (int j = 0; j < 8; ++j)
                g[j] = *(const uint*)(vB + ((size_t)(uint)e[j] << 7) + (c << 2));
#pragma unroll
            for (int j = 0; j < 8; ++j) {
                float w = __int_as_float((int)(e[j] >> 32));
                acc0 += w * bf2f((ushort)g[j]);
                acc1 += w * bf2f((ushort)(g[j] >> 16));
            }
            k += 8;
        }
    }
    for (; k < d; ++k) {
        ull e = __builtin_nontemporal_load(&eccq[s + k]);
        uint g = *(const uint*)(vB + ((size_t)(uint)e << 7) + (c << 2));
        float w = __int_as_float((int)(e >> 32));
        acc0 += w * bf2f((ushort)g);
        acc1 += w * bf2f((ushort)(g >> 16));
    }

    float di = dinv[i];
    float r0 = -a * di * acc0;
    float r1 = -a * di * acc1;
    if (bc != 0.f) {
        uint ov = *(const uint*)((const char*)other + ((size_t)(uint)i << 7) + (c << 2));
        r0 += bc * bf2f((ushort)ov);
        r1 += bc * bf2f((ushort)(ov >> 16));
    }
    uint pk = (uint)f2bf(r0) | ((uint)f2bf(r1) << 16);
    *(uint*)((char*)out + ((size_t)(uint)i << 7) + (c << 2)) = pk;
}

// ---------------- MFMA GEMM: C[N, NCT*16] = [A0|A1|A2] @ Wt^T + b ----------------
template <int NCT, bool RELU, bool BF16OUT>
__global__ __launch_bounds__(256) void k_gemm_mfma(const ushort* __restrict__ A0,
                                                   const ushort* __restrict__ A1,
                                                   const ushort* __restrict__ A2,
                                                   const ushort* __restrict__ Wt,
                                                   const float* __restrict__ bias,
                                                   int biasN,
                                                   ushort* __restrict__ outb,
                                                   float* __restrict__ outf, int N) {
    int lane = threadIdx.x & 63;
    int wv = blockIdx.x * 4 + (threadIdx.x >> 6);
    int nw = gridDim.x * 4;
    int r15 = lane & 15, kq = lane >> 4;

    bf16x8 bfr[6][NCT];
#pragma unroll
    for (int s = 0; s < 6; ++s)
#pragma unroll
        for (int ct = 0; ct < NCT; ++ct)
            bfr[s][ct] = *(const bf16x8*)(Wt + (size_t)(ct * 16 + r15) * 192 + s * 32 + kq * 8);
    float bs[NCT];
#pragma unroll
    for (int ct = 0; ct < NCT; ++ct) {
        int col = ct * 16 + r15;
        bs[ct] = (col < biasN) ? bias[col] : 0.f;
    }

    const ushort* As[3] = {A0, A1, A2};
    int ntile = N >> 4;
    if (wv >= ntile) return;
    bf16x8 af[6];
    {
        int rb = wv << 4;
#pragma unroll
        for (int s = 0; s < 6; ++s)
            af[s] = *(const bf16x8*)(As[s >> 1] + (size_t)(rb + r15) * 64 + (s & 1) * 32 + kq * 8);
    }
    for (int t = wv; t < ntile; t += nw) {
        int tn = t + nw;
        bf16x8 afn[6];
        if (tn < ntile) {
            int rbn = tn << 4;
#pragma unroll
            for (int s = 0; s < 6; ++s)
                afn[s] = *(const bf16x8*)(As[s >> 1] + (size_t)(rbn + r15) * 64 + (s & 1) * 32 + kq * 8);
        }
        f32x4 acc[NCT];
#pragma unroll
        for (int ct = 0; ct < NCT; ++ct) acc[ct] = (f32x4){0.f, 0.f, 0.f, 0.f};
#pragma unroll
        for (int s = 0; s < 6; ++s)
#pragma unroll
            for (int ct = 0; ct < NCT; ++ct)
                acc[ct] = __builtin_amdgcn_mfma_f32_16x16x32_bf16(af[s], bfr[s][ct], acc[ct], 0, 0, 0);
        int rb = t << 4;
#pragma unroll
        for (int ct = 0; ct < NCT; ++ct) {
            int col = ct * 16 + r15;
#pragma unroll
            for (int i = 0; i < 4; ++i) {
                int row = rb + kq * 4 + i;  // C/D: col=lane&15, row=(lane>>4)*4+i  [m89]
                float v = acc[ct][i] + bs[ct];
                if (RELU) v = fmaxf(v, 0.f);
                if (BF16OUT) {
                    outb[(size_t)row * 64 + col] = f2bf(v);
                } else {
                    if (col < 40) outf[(size_t)row * 40 + col] = v;
                }
            }
        }
#pragma unroll
        for (int s = 0; s < 6; ++s) af[s] = afn[s];
    }
}

extern "C" void kernel_launch(void* const* d_in, const int* in_sizes, int n_in,
                              void* d_out, int out_size, void* d_ws, size_t ws_size,
                              hipStream_t stream) {
    const float* x   = (const float*)d_in[0];
    const int*  eidx = (const int*)d_in[1];
    const float* W1  = (const float*)d_in[2];
    const float* b1  = (const float*)d_in[3];
    const float* W2  = (const float*)d_in[4];
    const float* b2  = (const float*)d_in[5];
    float* out = (float*)d_out;

    const int CIN = 50;
    int N = in_sizes[0] / CIN;  // 100000
    int E = in_sizes[1] / 2;    // 1600000
    const int* row = eidx;
    const int* col = eidx + E;

    int W = ((N + NW - 1) / NW + 1) & ~1;  // even window size (12500); must be <= 12800
    int WH = W >> 1;
    (void)WH;

    char* wsp = (char*)d_ws;
    auto carve = [&](size_t b) -> char* {
        char* p = wsp;
        wsp += (b + 255) & ~(size_t)255;
        return p;
    };
    int*    deg     = (int*)carve((size_t)N * 4);
    int*    startA  = (int*)carve((size_t)N * 4);
    int*    counter = (int*)carve(256);
    float*  dinv    = (float*)carve((size_t)N * 4);
    int2*   ecc     = (int2*)carve((size_t)E * 8);
    ushort* xb      = (ushort*)carve((size_t)N * 64 * 2);
    ushort* B1b     = (ushort*)carve((size_t)N * 64 * 2);
    ushort* B2b     = (ushort*)carve((size_t)N * 64 * 2);  // also aliased as histU
    ushort* Hb      = (ushort*)carve((size_t)N * 64 * 2);
    ushort* Wt1     = (ushort*)carve((size_t)64 * 192 * 2);
    ushort* Wt2     = (ushort*)carve((size_t)64 * 192 * 2);
    uint*   histU   = (uint*)B2b;  // NW*BSL*WH*4 = 6.4MB <= N*128B; consumed before lmul-2
    (void)ws_size; (void)n_in; (void)out_size;

    hipMemsetAsync(counter, 0, 4, stream);

    int gN = (N + 255) / 256;
    int gW2 = (N + 7) / 8;

    k_hist<<<NW * BSL, 1024, 0, stream>>>(row, histU, E, N, W);
    k_rowsum<<<((N + 1) / 2 + 255) / 256, 256, 0, stream>>>(histU, deg, dinv, N, W);
    k_alloc<<<gN, 256, 0, stream>>>(deg, startA, counter, N);
    k_fill2<<<NW * BSL, 1024, 0, stream>>>(row, col, startA, histU, dinv, ecc, E, N, W);
    k_pad_x<<<(N * 64 + 255) / 256, 256, 0, stream>>>(x, xb, N);
    k_wt<<<(2 * 64 * 192 + 255) / 256, 256, 0, stream>>>(W1, W2, Wt1, Wt2);

    int gG = 392;

    // layer 1
    k_lmul<<<gW2, 256, 0, stream>>>(startA, deg, ecc, dinv, xb, xb, B1b, N, 1.f, 0.f);
    k_lmul<<<gW2, 256, 0, stream>>>(startA, deg, ecc, dinv, B1b, xb, B2b, N, 2.f, -1.f);
    k_gemm_mfma<4, true, true><<<gG, 256, 0, stream>>>(xb, B1b, B2b, Wt1, b1, 50, Hb, nullptr, N);

    // layer 2
    k_lmul<<<gW2, 256, 0, stream>>>(startA, deg, ecc, dinv, Hb, Hb, B1b, N, 1.f, 0.f);
    k_lmul<<<gW2, 256, 0, stream>>>(startA, deg, ecc, dinv, B1b, Hb, B2b, N, 2.f, -1.f);
    k_gemm_mfma<3, false, false><<<gG, 256, 0, stream>>>(Hb, B1b, B2b, Wt2, b2, 40, nullptr, out, N);
}